// Round 7
// baseline (301.097 us; speedup 1.0000x reference)
//
#include <hip/hip_runtime.h>
#include <math.h>

typedef __attribute__((ext_vector_type(8))) _Float16 half8;
typedef __attribute__((ext_vector_type(4))) float    f32x4;

constexpr int D_DIM = 2048;
constexpr int NEXP  = 64;
constexpr int TOPK  = 8;
constexpr int NTOK  = 16384;        // B*S
constexpr int TM    = 64;           // tokens per WG
constexpr int BK    = 32;           // K per chunk (one 16x16x32 MFMA kstep)
constexpr int NCH   = D_DIM / BK;   // 64 chunks
constexpr int OSTR  = 132;          // logit tile row stride (floats)
constexpr int NSTR  = 68;           // noise tile row stride (floats)
constexpr float WSCALE  = 4096.0f;  // W pre-scale (keeps fp16 lo out of subnormals)
constexpr float INV_WSC = 1.0f / 4096.0f;

__device__ __forceinline__ unsigned short f16b(float x) {
    _Float16 h = (_Float16)x;                       // v_cvt_f16_f32 (RNE)
    return __builtin_bit_cast(unsigned short, h);
}
__device__ __forceinline__ float f16tof(unsigned short b) {
    return (float)__builtin_bit_cast(_Float16, b);
}

// async global->LDS, 16B per lane; dest = (wave-uniform base) + lane*16
__device__ __forceinline__ void async_cp16(const void* g, void* l) {
    __builtin_amdgcn_global_load_lds(
        (const __attribute__((address_space(1))) unsigned int*)g,
        (__attribute__((address_space(3))) unsigned int*)l, 16, 0, 0);
}

// ---------------------------------------------------------------------------
// K1: split W*4096 (gate rows 0..63, noise rows 64..127) into fp16 hi/lo.
// wsB layout per chunk c (16 KB = 8192 halfs):
//   [hi 4096 halfs: nt(0..7)*512 + lane*8 + j][lo 4096 halfs: same]
//   lane l holds B[k = c*32 + (l>>4)*8 + j][n = nt*16 + (l&15)]
// This linear order is exactly what the B DMA copies and what frag reads use.
// ---------------------------------------------------------------------------
__global__ void prep_w(const float* __restrict__ Wg, const float* __restrict__ Wn,
                       unsigned short* __restrict__ wsB)
{
    const int idx = blockIdx.x * blockDim.x + threadIdx.x;   // 0..32767
    const int n   = idx >> 8;      // output row 0..127
    const int K8  = idx & 255;     // k-octet
    const float* src = (n < 64) ? (Wg + (size_t)n * D_DIM)
                                : (Wn + (size_t)(n - 64) * D_DIM);
    float4 a = *reinterpret_cast<const float4*>(src + K8 * 8);
    float4 b = *reinterpret_cast<const float4*>(src + K8 * 8 + 4);

    float v[8] = {a.x, a.y, a.z, a.w, b.x, b.y, b.z, b.w};
    union { unsigned short u[8]; half8 s; } H, L;
#pragma unroll
    for (int j = 0; j < 8; ++j) {
        float xs = v[j] * WSCALE;
        unsigned short h = f16b(xs);
        H.u[j] = h;
        L.u[j] = f16b(xs - f16tof(h));
    }
    const int c  = K8 >> 2;                        // chunk
    const int l  = ((K8 & 3) * 16) + (n & 15);     // fragment lane
    const int nt = n >> 4;
    const size_t base = (size_t)c * 8192 + (size_t)nt * 512 + (size_t)l * 8;
    *reinterpret_cast<half8*>(wsB + base)        = H.s;
    *reinterpret_cast<half8*>(wsB + base + 4096) = L.s;
}

// ---------------------------------------------------------------------------
// K2: TM=64, N=128 per WG, grid 256 (1 WG/CU), 512 thr = 8 waves.
// Double-buffered global_load_lds staging (A fp32 frag-linear via gather
// source; B fp16 hi/lo linear from wsB). Wave w: rows (w>>2)*32, cols
// (w&3)*32 -> 2mt x 2nt tiles, accH+accX each, 12 MFMAs/chunk.
// DMAs for chunk c+1 issued at TOP of chunk c; barrier drain sees them
// ~full-chunk later -> only residual latency exposed.
// ---------------------------------------------------------------------------
__global__ __launch_bounds__(512, 1)
void noisy_topk_router(const float* __restrict__ hs,
                       const unsigned short* __restrict__ wsB,
                       const float* __restrict__ nz,
                       float* __restrict__ out)
{
    // stage: Abuf 2 x 8 KB @0, Bbuf 2 x 16 KB @16384  (48 KB)
    // epilogue union: logits 64x132 f32 @0 (33792 B), noise 64x68 f32 @33792
    __shared__ __align__(16) char smem[51200];
    float*          logits = reinterpret_cast<float*>(smem);
    float*          ldsN   = reinterpret_cast<float*>(smem + 33792);

    const int tid  = threadIdx.x;
    const int lane = tid & 63;
    const int w    = tid >> 6;          // 8 waves
    const int t0   = blockIdx.x * TM;
    const int mh   = w >> 2;            // row half (32 rows)
    const int nq   = w & 3;             // col quarter (32 cols)
    const int w4   = w - 4;

    // ---- DMA source addresses ----
    // A (waves 0..3): instr q in {0,1}: lane i reads h[t0 + q*32 + (i>>1)]
    //   [c*32 + w*8 + (i&1)*4 .. +4)  -> frag-linear fp32 LDS
    const float* aptr0 = hs + (size_t)(t0 + (lane >> 1)) * D_DIM      + w * 8 + (lane & 1) * 4;
    const float* aptr1 = hs + (size_t)(t0 + 32 + (lane >> 1)) * D_DIM + w * 8 + (lane & 1) * 4;
    // B (waves 4..7): 4 instrs, linear from wsB
    const unsigned short* bptr = wsB + (size_t)(w4 & 3) * 2048 + (size_t)lane * 8;

    auto issue_dma = [&](int c, int buf) {
        if (w < 4) {
            char* ad = smem + buf * 8192 + w * 2048;           // (w*2+q)*1024
            async_cp16(aptr0 + c * BK, ad);
            async_cp16(aptr1 + c * BK, ad + 1024);
        } else {
            const unsigned short* bs = bptr + (size_t)c * 8192;
            char* bd = smem + 16384 + buf * 16384 + w4 * 4096;
            async_cp16(bs,        bd);
            async_cp16(bs + 512,  bd + 1024);
            async_cp16(bs + 1024, bd + 2048);
            async_cp16(bs + 1536, bd + 3072);
        }
    };

    f32x4 accH[2][2], accX[2][2];
#pragma unroll
    for (int i = 0; i < 2; ++i)
#pragma unroll
        for (int j = 0; j < 2; ++j) {
            accH[i][j] = (f32x4){0.f, 0.f, 0.f, 0.f};
            accX[i][j] = (f32x4){0.f, 0.f, 0.f, 0.f};
        }

    // prologue: stage chunk 0 into buf 0
    issue_dma(0, 0);
    __syncthreads();

    for (int c = 0; c < NCH; ++c) {
        const int buf = c & 1;
        // 1. DMA for next chunk into the other buffer (issued first; its
        //    vmcnt drain happens at this chunk's END barrier, ~full chunk later)
        if (c + 1 < NCH)
            issue_dma(c + 1, buf ^ 1);

        // 2. A fragments: fp32 frag-linear LDS -> cvt to fp16 hi/lo
        const float*          ab = reinterpret_cast<const float*>(smem) + buf * 2048;
        const unsigned short* bb = reinterpret_cast<const unsigned short*>(smem + 16384) + buf * 8192;

        half8 ahi[2], alo[2], bhi[2], blo[2];
#pragma unroll
        for (int i = 0; i < 2; ++i) {
            const int mt = mh * 2 + i;
            const float* ap = ab + (lane >> 4) * 512 + (mt * 16 + (lane & 15)) * 8;
            float4 x0 = *reinterpret_cast<const float4*>(ap);
            float4 x1 = *reinterpret_cast<const float4*>(ap + 4);
            float xx[8] = {x0.x, x0.y, x0.z, x0.w, x1.x, x1.y, x1.z, x1.w};
            union { unsigned short u[8]; half8 v; } H, L;
#pragma unroll
            for (int j = 0; j < 8; ++j) {
                unsigned short h = f16b(xx[j]);
                H.u[j] = h;
                L.u[j] = f16b(xx[j] - f16tof(h));
            }
            ahi[i] = H.v;
            alo[i] = L.v;
        }
#pragma unroll
        for (int i = 0; i < 2; ++i) {
            const int nt = nq * 2 + i;
            bhi[i] = *reinterpret_cast<const half8*>(bb + nt * 512 + lane * 8);
            blo[i] = *reinterpret_cast<const half8*>(bb + 4096 + nt * 512 + lane * 8);
        }

        // 3. 12 MFMAs
#pragma unroll
        for (int i = 0; i < 2; ++i)
#pragma unroll
            for (int j = 0; j < 2; ++j) {
                accH[i][j] = __builtin_amdgcn_mfma_f32_16x16x32_f16(ahi[i], bhi[j], accH[i][j], 0, 0, 0);
                accX[i][j] = __builtin_amdgcn_mfma_f32_16x16x32_f16(ahi[i], blo[j], accX[i][j], 0, 0, 0);
                accX[i][j] = __builtin_amdgcn_mfma_f32_16x16x32_f16(alo[i], bhi[j], accX[i][j], 0, 0, 0);
            }

        __syncthreads();   // buf swap + DMA(c+1) drain (residual only)
    }

    // ---- epilogue: scatter accs to logit tile (stage LDS is dead) ----
    {
        const int rowq = (lane >> 4) * 4;
        const int colw = lane & 15;
#pragma unroll
        for (int i = 0; i < 2; ++i) {
            const int mt = mh * 2 + i;
#pragma unroll
            for (int j = 0; j < 2; ++j) {
                const int nt = nq * 2 + j;
#pragma unroll
                for (int r = 0; r < 4; ++r)
                    logits[(mt * 16 + rowq + r) * OSTR + nt * 16 + colw] =
                        (accH[i][j][r] + accX[i][j][r]) * INV_WSC;
            }
        }
    }
    // stage noise tile coalesced: 512 thr x 2 float4 = 64 rows x 64 floats
    {
        const int rr = tid >> 3;
        const int cc = tid & 7;
        const float* nrow = nz + (size_t)(t0 + rr) * NEXP;
#pragma unroll
        for (int p = 0; p < 2; ++p) {
            float4 v = *reinterpret_cast<const float4*>(nrow + cc * 4 + p * 32);
            *reinterpret_cast<float4*>(&ldsN[rr * NSTR + cc * 4 + p * 32]) = v;
        }
    }
    __syncthreads();

    if (tid < TM) {
        const int tok = t0 + tid;
        float l[NEXP];
        float mx = -3.0e38f;
#pragma unroll
        for (int e = 0; e < NEXP; ++e) {
            float gsc = logits[tid * OSTR + e];
            float nl  = logits[tid * OSTR + 64 + e];
            float sp  = fmaxf(nl, 0.0f) + log1pf(expf(-fabsf(nl)));   // softplus
            float le  = fmaf(ldsN[tid * NSTR + e], sp, gsc);
            l[e] = le;
            mx = fmaxf(mx, le);
        }
        float sum = 0.0f;
#pragma unroll
        for (int e = 0; e < NEXP; ++e) { float p = expf(l[e] - mx); l[e] = p; sum += p; }
        float inv = 1.0f / sum;
#pragma unroll
        for (int e = 0; e < NEXP; ++e) l[e] *= inv;

        // save gates for coalesced store
#pragma unroll
        for (int e = 0; e < NEXP; ++e) logits[tid * OSTR + e] = l[e];

        float* vout = out + (size_t)tok * TOPK;
        float* iout = out + (size_t)NTOK * TOPK + (size_t)tok * TOPK;
#pragma unroll
        for (int p = 0; p < TOPK; ++p) {
            float m = -1.0f; int mi = 0;
#pragma unroll
            for (int e = 0; e < NEXP; ++e) {
                bool gt = l[e] > m;        // strict > + ascending scan = lowest-index tie-break
                m  = gt ? l[e] : m;
                mi = gt ? e : mi;
            }
            vout[p] = m;
            iout[p] = (float)mi;
#pragma unroll
            for (int e = 0; e < NEXP; ++e) l[e] = (e == mi) ? -1.0f : l[e];
        }
    }
    __syncthreads();

    // coalesced gates store
    {
        const int rr = tid >> 3;
        const int cc = tid & 7;
        float* gout = out + (size_t)NTOK * TOPK * 2;
#pragma unroll
        for (int p = 0; p < 2; ++p) {
            float4 v = *reinterpret_cast<const float4*>(&logits[rr * OSTR + cc * 4 + p * 32]);
            *reinterpret_cast<float4*>(&gout[(size_t)(t0 + rr) * NEXP + cc * 4 + p * 32]) = v;
        }
    }
}

extern "C" void kernel_launch(void* const* d_in, const int* in_sizes, int n_in,
                              void* d_out, int out_size, void* d_ws, size_t ws_size,
                              hipStream_t stream) {
    const float* hs = (const float*)d_in[0];   // [4,4096,2048]
    const float* Wg = (const float*)d_in[1];   // [64,2048]
    const float* Wn = (const float*)d_in[2];   // [64,2048]
    const float* nz = (const float*)d_in[3];   // [4,4096,64]
    float* out = (float*)d_out;
    unsigned short* wsB = (unsigned short*)d_ws;   // 1 MB B-fragment pack (fp16 bits)

    prep_w<<<64, 512, 0, stream>>>(Wg, Wn, wsB);
    noisy_topk_router<<<NTOK / TM, 512, 0, stream>>>(hs, wsB, nz, out);
}